// Round 1
// baseline (372.828 us; speedup 1.0000x reference)
//
#include <hip/hip_runtime.h>
#include <stdint.h>

// GraphSAGE on MI355X.
// Pipeline (all bf16-MFMA GEMMs, f32 accumulate; mean-reductions in f32):
//   conv_w    : W1t[256][512] = [w1_self; w1_nbr]^T (bf16), same for W2t
//   fuse_mean : A1[100096][512] = [bf16(h1) | bf16(mean10(h2))]
//   fuse_mean : A0[10112][512]  = [bf16(h0) | bf16(mean10(h1))]
//   gemm      : nh1 = relu(A1 @ W1t^T)  [100096][256] bf16
//   gemm      : A2[:, :256] = relu(A0 @ W1t^T)       (nh0)
//   mean_bf16 : A2[:, 256:] = mean10(nh1)            (mnh1)
//   gemm      : out = A2 @ W2t^T  f32 [10000][256]

typedef unsigned short u16;
typedef __attribute__((ext_vector_type(4))) float f32x4;
typedef __attribute__((ext_vector_type(8))) short s16x8;
typedef __attribute__((ext_vector_type(4))) unsigned short u16x4;

__device__ inline u16 f2bf(float x) {
    union { float f; uint32_t u; } v; v.f = x;
    uint32_t b = v.u;
    b += 0x7FFFu + ((b >> 16) & 1u);   // round-to-nearest-even
    return (u16)(b >> 16);
}
__device__ inline float bf2f(u16 u) {
    union { uint32_t u; float f; } v; v.u = ((uint32_t)u) << 16;
    return v.f;
}

// Build Wt[n][k] (bf16), n in [0,256), k in [0,512):
//   k < 256 : wself[k][n] ; k >= 256 : wnbr[k-256][n]
__global__ __launch_bounds__(256) void conv_w(const float* __restrict__ wself,
                                              const float* __restrict__ wnbr,
                                              u16* __restrict__ Wt) {
    int idx = blockIdx.x * 256 + threadIdx.x;   // 0..131071
    int n = idx >> 9;
    int k = idx & 511;
    float v = (k < 256) ? wself[k * 256 + n] : wnbr[(k - 256) * 256 + n];
    Wt[idx] = f2bf(v);
}

// A[row][0:256] = bf16(self[row]); A[row][256:512] = bf16(mean_{j<10} nbr[row*10+j])
// one wave per row, lane handles 4 contiguous f32 columns (float4 loads)
__global__ __launch_bounds__(256) void fuse_mean(const float* __restrict__ self_rows,
                                                 const float* __restrict__ nbr_rows,
                                                 u16* __restrict__ A, int n) {
    int row = blockIdx.x * 4 + (threadIdx.x >> 6);
    if (row >= n) return;
    int lane = threadIdx.x & 63;
    int c = lane * 4;
    f32x4 acc = {0.f, 0.f, 0.f, 0.f};
    const float* nb = nbr_rows + (size_t)row * 10 * 256 + c;
    #pragma unroll
    for (int j = 0; j < 10; ++j)
        acc += *(const f32x4*)(nb + j * 256);
    f32x4 s = *(const f32x4*)(self_rows + (size_t)row * 256 + c);
    u16x4 sb, mb;
    #pragma unroll
    for (int i = 0; i < 4; ++i) { sb[i] = f2bf(s[i]); mb[i] = f2bf(acc[i] * 0.1f); }
    u16* out = A + (size_t)row * 512;
    *(u16x4*)(out + c) = sb;
    *(u16x4*)(out + 256 + c) = mb;
}

// out[row*ldo + c] = bf16(mean_{j<10} in[(row*10+j)*256 + c]) ; in is bf16
__global__ __launch_bounds__(256) void mean_bf16(const u16* __restrict__ in,
                                                 u16* __restrict__ out, int n, int ldo) {
    int row = blockIdx.x * 4 + (threadIdx.x >> 6);
    if (row >= n) return;
    int lane = threadIdx.x & 63;
    int c = lane * 4;
    float a[4] = {0.f, 0.f, 0.f, 0.f};
    const u16* nb = in + (size_t)row * 10 * 256 + c;
    #pragma unroll
    for (int j = 0; j < 10; ++j) {
        u16x4 v = *(const u16x4*)(nb + j * 256);
        #pragma unroll
        for (int i = 0; i < 4; ++i) a[i] += bf2f(v[i]);
    }
    u16x4 o;
    #pragma unroll
    for (int i = 0; i < 4; ++i) o[i] = f2bf(a[i] * 0.1f);
    *(u16x4*)(out + (size_t)row * ldo + c) = o;
}

// C[M][ldc] = (relu?)(A[Mpad][512] @ Bt[256][512]^T), 128x128 tile, BK=64,
// 4 waves 2x2, global_load_lds(16B) staging, mfma_f32_16x16x32_bf16.
template <bool RELU, bool OUTF32>
__global__ __launch_bounds__(256) void gemm_k512(const u16* __restrict__ A,
                                                 const u16* __restrict__ Bt,
                                                 void* __restrict__ C,
                                                 int ldc, int Mstore) {
    __shared__ u16 lA[128 * 64];
    __shared__ u16 lB[128 * 64];
    const int bn = blockIdx.x;            // 0..1  (fastest: L2 reuse of A panel)
    const int bm = blockIdx.y;
    const int tid = threadIdx.x;
    const int lane = tid & 63;
    const int wave = tid >> 6;
    const int wr = wave >> 1, wc = wave & 1;

    f32x4 acc[4][4] = {};

    const size_t a_base = (size_t)(bm * 128) * 512;

    for (int kt = 0; kt < 8; ++kt) {
        const int k0 = kt * 64;
        #pragma unroll
        for (int p = 0; p < 4; ++p) {               // stage A: 16 KB
            int cch = p * 256 + tid;                // 16B chunk id
            int row = cch >> 3;
            int ke = (cch & 7) * 8;
            const u16* gp = A + a_base + (size_t)row * 512 + k0 + ke;
            u16* lp = lA + (size_t)(p * 256 + wave * 64) * 8;   // wave-uniform base
            __builtin_amdgcn_global_load_lds((const __attribute__((address_space(1))) void*)gp,
                                             (__attribute__((address_space(3))) void*)lp,
                                             16, 0, 0);
        }
        #pragma unroll
        for (int p = 0; p < 4; ++p) {               // stage B: 16 KB
            int cch = p * 256 + tid;
            int row = cch >> 3;
            int ke = (cch & 7) * 8;
            const u16* gp = Bt + (size_t)(bn * 128 + row) * 512 + k0 + ke;
            u16* lp = lB + (size_t)(p * 256 + wave * 64) * 8;
            __builtin_amdgcn_global_load_lds((const __attribute__((address_space(1))) void*)gp,
                                             (__attribute__((address_space(3))) void*)lp,
                                             16, 0, 0);
        }
        __syncthreads();
        #pragma unroll
        for (int ks = 0; ks < 2; ++ks) {
            s16x8 aF[4], bF[4];
            #pragma unroll
            for (int m = 0; m < 4; ++m)
                aF[m] = *(const s16x8*)&lA[(wr * 64 + m * 16 + (lane & 15)) * 64 + ks * 32 + (lane >> 4) * 8];
            #pragma unroll
            for (int nn = 0; nn < 4; ++nn)
                bF[nn] = *(const s16x8*)&lB[(wc * 64 + nn * 16 + (lane & 15)) * 64 + ks * 32 + (lane >> 4) * 8];
            #pragma unroll
            for (int m = 0; m < 4; ++m)
                #pragma unroll
                for (int nn = 0; nn < 4; ++nn)
                    acc[m][nn] = __builtin_amdgcn_mfma_f32_16x16x32_bf16(aF[m], bF[nn], acc[m][nn], 0, 0, 0);
        }
        __syncthreads();
    }

    // C/D layout: col = lane&15, row = (lane>>4)*4 + j   [m89-verified]
    const int row0 = bm * 128 + wr * 64 + (lane >> 4) * 4;
    const int col0 = bn * 128 + wc * 64 + (lane & 15);
    #pragma unroll
    for (int m = 0; m < 4; ++m) {
        #pragma unroll
        for (int nn = 0; nn < 4; ++nn) {
            #pragma unroll
            for (int j = 0; j < 4; ++j) {
                int r = row0 + m * 16 + j;
                if (r >= Mstore) continue;
                int cc = col0 + nn * 16;
                float v = acc[m][nn][j];
                if (RELU) v = fmaxf(v, 0.f);
                if (OUTF32) ((float*)C)[(size_t)r * ldc + cc] = v;
                else        ((u16*)C)[(size_t)r * ldc + cc] = f2bf(v);
            }
        }
    }
}

extern "C" void kernel_launch(void* const* d_in, const int* in_sizes, int n_in,
                              void* d_out, int out_size, void* d_ws, size_t ws_size,
                              hipStream_t stream) {
    const float* h0  = (const float*)d_in[0];
    const float* h1  = (const float*)d_in[1];
    const float* h2  = (const float*)d_in[2];
    const float* w1s = (const float*)d_in[3];
    const float* w1n = (const float*)d_in[4];
    const float* w2s = (const float*)d_in[5];
    const float* w2n = (const float*)d_in[6];

    const int N0 = 10000;                 // hop-0 nodes
    const int N1 = 100000;                // hop-1 nodes
    const int M1pad = 100096;             // 782 * 128
    const int M0pad = 10112;              // 79 * 128

    char* ws = (char*)d_ws;
    u16* W1t = (u16*)ws; ws += (size_t)256 * 512 * 2;
    u16* W2t = (u16*)ws; ws += (size_t)256 * 512 * 2;
    u16* A1  = (u16*)ws; ws += (size_t)M1pad * 512 * 2;
    u16* nh1 = (u16*)ws; ws += (size_t)M1pad * 256 * 2;
    u16* A0  = (u16*)ws; ws += (size_t)M0pad * 512 * 2;
    u16* A2  = (u16*)ws; ws += (size_t)M0pad * 512 * 2;
    (void)ws_size; (void)in_sizes; (void)n_in; (void)out_size;

    conv_w<<<512, 256, 0, stream>>>(w1s, w1n, W1t);
    conv_w<<<512, 256, 0, stream>>>(w2s, w2n, W2t);

    fuse_mean<<<(N1 + 3) / 4, 256, 0, stream>>>(h1, h2, A1, N1);
    fuse_mean<<<(N0 + 3) / 4, 256, 0, stream>>>(h0, h1, A0, N0);

    // layer 1, hop 1: nh1 = relu(A1 @ W1)   [100096][256] bf16
    gemm_k512<true, false><<<dim3(2, M1pad / 128), 256, 0, stream>>>(A1, W1t, nh1, 256, M1pad);
    // layer 1, hop 0: nh0 -> A2[:, 0:256]
    gemm_k512<true, false><<<dim3(2, M0pad / 128), 256, 0, stream>>>(A0, W1t, A2, 512, M0pad);
    // mnh1 -> A2[:, 256:512]
    mean_bf16<<<(N0 + 3) / 4, 256, 0, stream>>>(nh1, A2 + 256, N0, 512);
    // layer 2: out = A2 @ W2, f32, store only first 10000 rows
    gemm_k512<false, true><<<dim3(2, M0pad / 128), 256, 0, stream>>>(A2, W2t, d_out, 256, N0);
}

// Round 2
// 322.267 us; speedup vs baseline: 1.1569x; 1.1569x over previous
//
#include <hip/hip_runtime.h>
#include <stdint.h>

// GraphSAGE on MI355X — fused pipeline (4 launches):
//   conv_w2   : W1t[256][512]=[w1s;w1n]^T bf16, W2t likewise
//   sage_gemm : nh1 = relu([h1 | mean10(h2)] @ W1t^T)   f32 in, bf16 out
//   sage_gemm : nh0 = relu([h0 | mean10(h1)] @ W1t^T)   f32 in, bf16 out
//   sage_gemm : out = [nh0 | mean10(nh1)] @ W2t^T       bf16 in, f32 out
// Each sage_gemm block builds its A-tile [32][512] (self | neighbor-mean)
// in LDS on the fly — no materialized A buffers, no intermediate means.

typedef unsigned short u16;
typedef __attribute__((ext_vector_type(4))) float f32x4;
typedef __attribute__((ext_vector_type(8))) short s16x8;
typedef __attribute__((ext_vector_type(4))) unsigned short u16x4;

__device__ inline u16 f2bf(float x) {
    union { float f; uint32_t u; } v; v.f = x;
    uint32_t b = v.u;
    b += 0x7FFFu + ((b >> 16) & 1u);   // round-to-nearest-even
    return (u16)(b >> 16);
}
__device__ inline float bf2f(u16 u) {
    union { uint32_t u; float f; } v; v.u = ((uint32_t)u) << 16;
    return v.f;
}

// Both weight matrices -> bf16, transposed+stacked: Wt[n][k], k<256 self, k>=256 nbr
__global__ __launch_bounds__(256) void conv_w2(const float* __restrict__ w1s,
                                               const float* __restrict__ w1n,
                                               const float* __restrict__ w2s,
                                               const float* __restrict__ w2n,
                                               u16* __restrict__ W1t,
                                               u16* __restrict__ W2t) {
    int idx = blockIdx.x * 256 + threadIdx.x;    // 0..262143
    int which = idx >> 17;
    int i = idx & 131071;
    int n = i >> 9;
    int k = i & 511;
    const float* wsp = which ? w2s : w1s;
    const float* wnp = which ? w2n : w1n;
    u16* o = which ? W2t : W1t;
    float v = (k < 256) ? wsp[k * 256 + n] : wnp[(k - 256) * 256 + n];
    o[i] = f2bf(v);
}

// ---- swizzled LDS A-tile helpers: lA[32][512] bf16, 1024 B/row, 64 16B-chunks/row
// physical chunk = logical chunk ^ (row & 7)  -> conflict-free ds_read_b128 frags
__device__ inline void store_lA(u16* lA, int r, int c, u16x4 v) {   // c mult of 4
    int byte = c * 2;
    int chunk = byte >> 4;
    int off = byte & 15;
    char* p = (char*)(lA + (size_t)r * 512) + ((chunk ^ (r & 7)) * 16) + off;
    *(u16x4*)p = v;
}
__device__ inline s16x8 read_lA(const u16* lA, int r, int k) {      // k mult of 8
    int chunk = (k * 2) >> 4;
    const char* p = (const char*)(lA + (size_t)r * 512) + ((chunk ^ (r & 7)) * 16);
    return *(const s16x8*)p;
}

// Fused SAGE layer: C[32 rows/block][256] = act([self | mean10(nbr)] @ Bt^T)
// SELF_F32/NBR_F32 select input dtype (f32 vs bf16). B read direct from L2.
template <bool SELF_F32, bool NBR_F32, bool RELU, bool OUTF32>
__global__ __launch_bounds__(256, 4) void sage_gemm(const void* __restrict__ selfp,
                                                    const void* __restrict__ nbrp,
                                                    const u16* __restrict__ Bt,
                                                    void* __restrict__ C,
                                                    int Nrows, int Mstore) {
    __shared__ __align__(16) u16 lA[32 * 512];     // 32 KB
    const int tid = threadIdx.x;
    const int lane = tid & 63;
    const int wave = tid >> 6;
    const int row0 = blockIdx.x * 32;

    // ---- phase 0a: self columns 0..255
    #pragma unroll
    for (int p = 0; p < 8; ++p) {
        int chunk = p * 256 + tid;                 // 2048 chunks of 4 cols
        int r = chunk >> 6;
        int c4 = (chunk & 63) * 4;
        int gr = min(row0 + r, Nrows - 1);
        u16x4 sb;
        if (SELF_F32) {
            f32x4 v = *(const f32x4*)((const float*)selfp + (size_t)gr * 256 + c4);
            #pragma unroll
            for (int i = 0; i < 4; ++i) sb[i] = f2bf(v[i]);
        } else {
            sb = *(const u16x4*)((const u16*)selfp + (size_t)gr * 256 + c4);
        }
        store_lA(lA, r, c4, sb);
    }
    // ---- phase 0b: neighbor mean -> columns 256..511
    #pragma unroll
    for (int p = 0; p < 8; ++p) {
        int chunk = p * 256 + tid;
        int r = chunk >> 6;
        int c4 = (chunk & 63) * 4;
        int gr = min(row0 + r, Nrows - 1);
        f32x4 acc = {0.f, 0.f, 0.f, 0.f};
        if (NBR_F32) {
            const float* nb = (const float*)nbrp + (size_t)gr * 10 * 256 + c4;
            #pragma unroll
            for (int j = 0; j < 10; ++j)
                acc += *(const f32x4*)(nb + (size_t)j * 256);
        } else {
            const u16* nb = (const u16*)nbrp + (size_t)gr * 10 * 256 + c4;
            #pragma unroll
            for (int j = 0; j < 10; ++j) {
                u16x4 v = *(const u16x4*)(nb + (size_t)j * 256);
                #pragma unroll
                for (int i = 0; i < 4; ++i) acc[i] += bf2f(v[i]);
            }
        }
        u16x4 mb;
        #pragma unroll
        for (int i = 0; i < 4; ++i) mb[i] = f2bf(acc[i] * 0.1f);
        store_lA(lA, r, 256 + c4, mb);
    }
    __syncthreads();

    // ---- phase 1: K=512 MFMA sweep; B fragments straight from L2 (weights resident)
    f32x4 acc[2][4] = {};
    const int an = lane & 15;
    const int ak = (lane >> 4) * 8;
    const u16* bp[4];
    #pragma unroll
    for (int nn = 0; nn < 4; ++nn)
        bp[nn] = Bt + (size_t)(wave * 64 + nn * 16 + an) * 512 + ak;

    for (int kt = 0; kt < 8; ++kt) {
        const int kbase = kt * 64;
        s16x8 bF[2][4];
        #pragma unroll
        for (int ks = 0; ks < 2; ++ks)
            #pragma unroll
            for (int nn = 0; nn < 4; ++nn)
                bF[ks][nn] = *(const s16x8*)(bp[nn] + kbase + ks * 32);
        #pragma unroll
        for (int ks = 0; ks < 2; ++ks) {
            s16x8 aF[2];
            #pragma unroll
            for (int m = 0; m < 2; ++m)
                aF[m] = read_lA(lA, m * 16 + an, kbase + ks * 32 + ak);
            #pragma unroll
            for (int m = 0; m < 2; ++m)
                #pragma unroll
                for (int nn = 0; nn < 4; ++nn)
                    acc[m][nn] = __builtin_amdgcn_mfma_f32_16x16x32_bf16(aF[m], bF[ks][nn], acc[m][nn], 0, 0, 0);
        }
    }

    // ---- epilogue: C/D layout col=lane&15, row=(lane>>4)*4+j  [m89-verified]
    const int orow0 = row0 + (lane >> 4) * 4;
    const int col0 = wave * 64 + (lane & 15);
    #pragma unroll
    for (int m = 0; m < 2; ++m) {
        #pragma unroll
        for (int nn = 0; nn < 4; ++nn) {
            #pragma unroll
            for (int j = 0; j < 4; ++j) {
                int r = orow0 + m * 16 + j;
                if (r >= Mstore) continue;
                int cc = col0 + nn * 16;
                float v = acc[m][nn][j];
                if (RELU) v = fmaxf(v, 0.f);
                if (OUTF32) ((float*)C)[(size_t)r * 256 + cc] = v;
                else        ((u16*)C)[(size_t)r * 256 + cc] = f2bf(v);
            }
        }
    }
}

extern "C" void kernel_launch(void* const* d_in, const int* in_sizes, int n_in,
                              void* d_out, int out_size, void* d_ws, size_t ws_size,
                              hipStream_t stream) {
    const float* h0  = (const float*)d_in[0];
    const float* h1  = (const float*)d_in[1];
    const float* h2  = (const float*)d_in[2];
    const float* w1s = (const float*)d_in[3];
    const float* w1n = (const float*)d_in[4];
    const float* w2s = (const float*)d_in[5];
    const float* w2n = (const float*)d_in[6];

    const int N0 = 10000;
    const int N1 = 100000;

    char* ws = (char*)d_ws;
    u16* W1t = (u16*)ws; ws += (size_t)256 * 512 * 2;
    u16* W2t = (u16*)ws; ws += (size_t)256 * 512 * 2;
    u16* nh1 = (u16*)ws; ws += (size_t)N1 * 256 * 2;
    u16* nh0 = (u16*)ws; ws += (size_t)10016 * 256 * 2;
    (void)ws_size; (void)in_sizes; (void)n_in; (void)out_size;

    conv_w2<<<1024, 256, 0, stream>>>(w1s, w1n, w2s, w2n, W1t, W2t);

    // layer 1, hop 1: nh1 = relu([h1 | mean10(h2)] @ W1)   100000 rows, 3125 blocks exact
    sage_gemm<true, true, true, false><<<3125, 256, 0, stream>>>(h1, h2, W1t, nh1, N1, N1);
    // layer 1, hop 0: nh0 = relu([h0 | mean10(h1)] @ W1)   10000 rows, 313 blocks (tail-clamped)
    sage_gemm<true, true, true, false><<<313, 256, 0, stream>>>(h0, h1, W1t, nh0, N0, N0);
    // layer 2: out = [nh0 | mean10(nh1)] @ W2, f32 out
    sage_gemm<false, false, false, true><<<313, 256, 0, stream>>>(nh0, nh1, W2t, d_out, N0, N0);
}